// Round 6
// baseline (409.795 us; speedup 1.0000x reference)
//
#include <hip/hip_runtime.h>
#include <hip/hip_cooperative_groups.h>

namespace cg = cooperative_groups;

typedef unsigned short u16;
typedef _Float16 f16;
typedef __attribute__((ext_vector_type(8))) short v8s;
typedef __attribute__((ext_vector_type(4))) short v4s;
typedef __attribute__((ext_vector_type(8))) f16   v8h;
typedef __attribute__((ext_vector_type(4))) float v4f;
typedef __attribute__((ext_vector_type(16))) float v16f;
typedef __attribute__((ext_vector_type(4))) unsigned v4u;

#define NB   8
#define NC   256
#define DQK  32
#define NPIX 4096

__device__ __forceinline__ u16 f2bf(float f) {
  unsigned u = __builtin_bit_cast(unsigned, f);
  u += 0x7FFFu + ((u >> 16) & 1u);   // RNE
  return (u16)(u >> 16);
}
__device__ __forceinline__ u16 f2h(float f) {
  return __builtin_bit_cast(u16, (f16)f);   // v_cvt_f16_f32, RNE
}
__device__ __forceinline__ unsigned cvt_pk_bf16(float lo, float hi) {
  unsigned r;
  asm("v_cvt_pk_bf16_f32 %0, %1, %2" : "=v"(r) : "v"(lo), "v"(hi));
  return r;
}
// raw v_exp_f32: exponents here are in ~[-91,-18] -> normal range, no ocml fixup needed
__device__ __forceinline__ float fast_exp2(float x) {
  float r;
  asm("v_exp_f32 %0, %1" : "=v"(r) : "v"(x));
  return r;
}

#define L2E  1.44269504f
#define SHFT -48.0f

// From S tile (32 kv) produce PV B-frags for its two 16-kv blocks.
// reg r of S: kv = (r&3) + 8*(r>>2) + 4*(lane>>5).
#define PACK_TILE(S, PBLO, PBHI)                                              \
  {                                                                           \
    float e0  = fast_exp2(fmaf(S[0],  L2E, SHFT));                            \
    float e1  = fast_exp2(fmaf(S[1],  L2E, SHFT));                            \
    float e2  = fast_exp2(fmaf(S[2],  L2E, SHFT));                            \
    float e3  = fast_exp2(fmaf(S[3],  L2E, SHFT));                            \
    float e4  = fast_exp2(fmaf(S[4],  L2E, SHFT));                            \
    float e5  = fast_exp2(fmaf(S[5],  L2E, SHFT));                            \
    float e6  = fast_exp2(fmaf(S[6],  L2E, SHFT));                            \
    float e7  = fast_exp2(fmaf(S[7],  L2E, SHFT));                            \
    float e8  = fast_exp2(fmaf(S[8],  L2E, SHFT));                            \
    float e9  = fast_exp2(fmaf(S[9],  L2E, SHFT));                            \
    float e10 = fast_exp2(fmaf(S[10], L2E, SHFT));                            \
    float e11 = fast_exp2(fmaf(S[11], L2E, SHFT));                            \
    float e12 = fast_exp2(fmaf(S[12], L2E, SHFT));                            \
    float e13 = fast_exp2(fmaf(S[13], L2E, SHFT));                            \
    float e14 = fast_exp2(fmaf(S[14], L2E, SHFT));                            \
    float e15 = fast_exp2(fmaf(S[15], L2E, SHFT));                            \
    lsum += (((e0 + e1) + (e2 + e3)) + ((e4 + e5) + (e6 + e7)))               \
          + (((e8 + e9) + (e10 + e11)) + ((e12 + e13) + (e14 + e15)));        \
    unsigned u00 = cvt_pk_bf16(e0,  e1),  u01 = cvt_pk_bf16(e2,  e3);         \
    unsigned u10 = cvt_pk_bf16(e4,  e5),  u11 = cvt_pk_bf16(e6,  e7);         \
    unsigned u20 = cvt_pk_bf16(e8,  e9),  u21 = cvt_pk_bf16(e10, e11);        \
    unsigned u30 = cvt_pk_bf16(e12, e13), u31 = cvt_pk_bf16(e14, e15);        \
    asm("v_permlane32_swap_b32 %0, %1" : "+v"(u00), "+v"(u10));               \
    asm("v_permlane32_swap_b32 %0, %1" : "+v"(u01), "+v"(u11));               \
    asm("v_permlane32_swap_b32 %0, %1" : "+v"(u20), "+v"(u30));               \
    asm("v_permlane32_swap_b32 %0, %1" : "+v"(u21), "+v"(u31));               \
    PBLO = __builtin_bit_cast(v8s, (v4u){u00, u01, u10, u11});                \
    PBHI = __builtin_bit_cast(v8s, (v4u){u20, u21, u30, u31});                \
  }

// stage one 64kv x 256ch V tile slice (8 frags of this wave) into LDS buffer BUF
#define STAGE(IT, BUF)                                                        \
  {                                                                           \
    _Pragma("unroll")                                                         \
    for (int j = 0; j < 8; ++j) {                                             \
      const int f = wq * 8 + j;                                               \
      __builtin_amdgcn_global_load_lds(                                       \
          (const __attribute__((address_space(1))) unsigned*)(Vg + ((size_t)(IT) * 32 + f) * 512), \
          (__attribute__((address_space(3))) unsigned*)(&SB[BUF][f][0][0]), 16, 0, 0); \
    }                                                                         \
  }

// One attn kv-step.  Order: barrier gate -> stage(I+1) -> S(I+1)+PACK(I+1)
// into the OTHER P set (runs in PV's MFMA shadow) -> kc reload (I+2) -> PV(I).
#define ASTEP(I, PP, PI0, PI1, PI2, PI3, PO0, PO1, PO2, PO3)                  \
  {                                                                           \
    __builtin_amdgcn_sched_barrier(0);                                        \
    if ((I) < 31) { asm volatile("s_waitcnt vmcnt(4)" ::: "memory"); }        \
    else          { asm volatile("s_waitcnt vmcnt(0)" ::: "memory"); }        \
    __builtin_amdgcn_s_barrier();                                             \
    __builtin_amdgcn_sched_barrier(0);                                        \
    if ((I) < 31) {                                                           \
      STAGE((I) + 1, bufbase + ((PP) ^ 1));                                   \
      v16f sA = __builtin_amdgcn_mfma_f32_32x32x16_f16(kc0, qf0, vz, 0, 0, 0);\
      sA = __builtin_amdgcn_mfma_f32_32x32x16_f16(kc1, qf1, sA, 0, 0, 0);     \
      PACK_TILE(sA, PO0, PO1);                                                \
      v16f sB = __builtin_amdgcn_mfma_f32_32x32x16_f16(kc2, qf0, vz, 0, 0, 0);\
      sB = __builtin_amdgcn_mfma_f32_32x32x16_f16(kc3, qf1, sB, 0, 0, 0);     \
      PACK_TILE(sB, PO2, PO3);                                                \
    }                                                                         \
    if ((I) < 30) {  /* reload kc in place with K(I+2); S(I+1) already read it */ \
      const u16* kp2 = Kp + (size_t)((I) + 2) * 2048;                         \
      kc0 = *(const v8h*)(kp2);                                               \
      kc1 = *(const v8h*)(kp2 + 16);                                          \
      kc2 = *(const v8h*)(kp2 + 1024);                                        \
      kc3 = *(const v8h*)(kp2 + 1040);                                        \
    }                                                                         \
    __builtin_amdgcn_s_setprio(1);                                            \
    _Pragma("unroll")                                                         \
    for (int ct = 0; ct < 8; ++ct) {                                          \
      v8s vf0 = *(const v8s*)(&SB[bufbase + (PP)][ct * 4 + 0][lane][0]);      \
      v8s vf1 = *(const v8s*)(&SB[bufbase + (PP)][ct * 4 + 1][lane][0]);      \
      v8s vf2 = *(const v8s*)(&SB[bufbase + (PP)][ct * 4 + 2][lane][0]);      \
      v8s vf3 = *(const v8s*)(&SB[bufbase + (PP)][ct * 4 + 3][lane][0]);      \
      acc[ct] = __builtin_amdgcn_mfma_f32_32x32x16_bf16(vf0, PI0, acc[ct], 0, 0, 0); \
      acc[ct] = __builtin_amdgcn_mfma_f32_32x32x16_bf16(vf1, PI1, acc[ct], 0, 0, 0); \
      acc[ct] = __builtin_amdgcn_mfma_f32_32x32x16_bf16(vf2, PI2, acc[ct], 0, 0, 0); \
      acc[ct] = __builtin_amdgcn_mfma_f32_32x32x16_bf16(vf3, PI3, acc[ct], 0, 0, 0); \
    }                                                                         \
    __builtin_amdgcn_s_setprio(0);                                            \
  }

// ---- Single cooperative kernel: convert -> sync -> proj -> sync -> attn ----
// 256 blocks x 512 thr, 1 block/CU (128.5 KB LDS).  Block B: b = B&7 (XCD-
// affine), 128-pixel chunk = (B>>3)*128 (its own attn q-rows).
__global__ __launch_bounds__(512, 2)
void fused_all(const float* __restrict__ x, const float* __restrict__ y,
               const float* __restrict__ Wq, const float* __restrict__ bq,
               const float* __restrict__ Wk, const float* __restrict__ bk,
               const float* __restrict__ Wv, const float* __restrict__ bv,
               u16* __restrict__ Qb, u16* __restrict__ Kb, u16* __restrict__ Vt,
               u16* __restrict__ Whq, u16* __restrict__ Whk, u16* __restrict__ Whv,
               float* __restrict__ out) {
  __shared__ __attribute__((aligned(16))) u16 SB[4][32][64][8];   // 128 KiB (union)
  __shared__ float Ls2[4][32];

  const int tid  = threadIdx.x;
  const int w    = tid >> 6;      // 0..7
  const int lane = tid & 63;
  const int lr   = lane & 15;
  const int quad = lane >> 4;
  const int b    = blockIdx.x & 7;
  const int n0   = (blockIdx.x >> 3) * 128;

  // ================= phase 0: W fp32 -> fp16 =================
  {
    int i = blockIdx.x * 512 + tid;   // 0..131071
    if (i < 8192)       Whq[i]         = f2h(Wq[i]);
    else if (i < 16384) Whk[i - 8192]  = f2h(Wk[i - 8192]);
    else if (i < 81920) Whv[i - 16384] = f2h(Wv[i - 16384]);
  }
  __threadfence();
  cg::this_grid().sync();

  // ================= phase 1: fused transpose + Q/K/V projections =========
  // LDS: Tx/Ty [128 px][88 u16] (stride 176 B: bank-even b128 reads+writes)
  {
    u16 (*Tx)[88] = reinterpret_cast<u16 (*)[88]>(&SB[0][0][0][0]);
    u16 (*Ty)[88] = Tx + 128;

    const int col = w * 16 + lr;                 // gather pixel column 0..127
    const int n = n0 + col;
    const size_t bn = ((size_t)b << 12) + n;
    const int srow  = (w >> 2) * 64 + lane;      // staging row 0..127
    const int scol0 = (w & 3) * 16;              // staging c base within tile
    const float* __restrict__ xs = x + ((size_t)b << 20) + n0 + srow;
    const float* __restrict__ ys = y + ((size_t)b << 20) + n0 + srow;

    v4f aq[2], ak[2], av[16];
#pragma unroll
    for (int ot = 0; ot < 2; ++ot) { aq[ot] = (v4f){0.f,0.f,0.f,0.f}; ak[ot] = (v4f){0.f,0.f,0.f,0.f}; }
#pragma unroll
    for (int vt = 0; vt < 16; ++vt) av[vt] = (v4f){0.f,0.f,0.f,0.f};

    float xv[16], yv[16];
#pragma unroll
    for (int i = 0; i < 16; ++i) {               // preload cs=0
      xv[i] = xs[(size_t)(scol0 + i) * NPIX];
      yv[i] = ys[(size_t)(scol0 + i) * NPIX];
    }

#pragma unroll 1
    for (int cs = 0; cs < 4; ++cs) {
      __syncthreads();                           // prior gathers done / LDS free
      v8s hx0, hx1, hy0, hy1;
#pragma unroll
      for (int i = 0; i < 8; ++i) {
        hx0[i] = (short)f2h(xv[i]);     hx1[i] = (short)f2h(xv[8 + i]);
        hy0[i] = (short)f2h(yv[i]);     hy1[i] = (short)f2h(yv[8 + i]);
      }
      *(v8s*)(&Tx[srow][scol0])     = hx0;       // bank-even b128 writes
      *(v8s*)(&Tx[srow][scol0 + 8]) = hx1;
      *(v8s*)(&Ty[srow][scol0])     = hy0;
      *(v8s*)(&Ty[srow][scol0 + 8]) = hy1;
      if (cs < 3) {                              // T14: prefetch next subtile
#pragma unroll
        for (int i = 0; i < 16; ++i) {
          xv[i] = xs[(size_t)((cs + 1) * 64 + scol0 + i) * NPIX];
          yv[i] = ys[(size_t)((cs + 1) * 64 + scol0 + i) * NPIX];
        }
      }
      __syncthreads();                           // tile ready

      const v8h xb0 = *(const v8h*)(&Tx[col][quad * 8]);        // b128 gathers
      const v8h xb1 = *(const v8h*)(&Tx[col][32 + quad * 8]);
      const v8h yb0 = *(const v8h*)(&Ty[col][quad * 8]);
      const v8h yb1 = *(const v8h*)(&Ty[col][32 + quad * 8]);

#pragma unroll
      for (int ot = 0; ot < 2; ++ot) {
        const u16* wqp = Whq + (ot * 16 + lr) * 256 + cs * 64 + quad * 8;
        const u16* wkp = Whk + (ot * 16 + lr) * 256 + cs * 64 + quad * 8;
        aq[ot] = __builtin_amdgcn_mfma_f32_16x16x32_f16(*(const v8h*)(wqp),      xb0, aq[ot], 0, 0, 0);
        aq[ot] = __builtin_amdgcn_mfma_f32_16x16x32_f16(*(const v8h*)(wqp + 32), xb1, aq[ot], 0, 0, 0);
        ak[ot] = __builtin_amdgcn_mfma_f32_16x16x32_f16(*(const v8h*)(wkp),      yb0, ak[ot], 0, 0, 0);
        ak[ot] = __builtin_amdgcn_mfma_f32_16x16x32_f16(*(const v8h*)(wkp + 32), yb1, ak[ot], 0, 0, 0);
      }
#pragma unroll
      for (int vt = 0; vt < 16; ++vt) {
        const u16* wvp = Whv + (vt * 16 + lr) * 256 + cs * 64 + quad * 8;
        av[vt] = __builtin_amdgcn_mfma_f32_16x16x32_f16(*(const v8h*)(wvp),      yb0, av[vt], 0, 0, 0);
        av[vt] = __builtin_amdgcn_mfma_f32_16x16x32_f16(*(const v8h*)(wvp + 32), yb1, av[vt], 0, 0, 0);
      }
    }

    // Q/K bias + fp16 store (pixel-major [n][32])
#pragma unroll
    for (int ot = 0; ot < 2; ++ot) {
      v4f bqv = *(const v4f*)(bq + ot * 16 + quad * 4);
      v4f bkv = *(const v4f*)(bk + ot * 16 + quad * 4);
      v4s q4, k4;
#pragma unroll
      for (int r = 0; r < 4; ++r) {
        q4[r] = (short)f2h(aq[ot][r] + bqv[r]);
        k4[r] = (short)f2h(ak[ot][r] + bkv[r]);
      }
      *(v4s*)(Qb + bn * DQK + ot * 16 + quad * 4) = q4;
      *(v4s*)(Kb + bn * DQK + ot * 16 + quad * 4) = k4;
    }
    // V bias + frag-linear bf16 store
#pragma unroll
    for (int vt = 0; vt < 16; ++vt) {
#pragma unroll
      for (int r = 0; r < 4; ++r) {
        int o = vt * 16 + quad * 4 + r;
        size_t off = ((((size_t)b * 64 + (n >> 6)) * 32 + (o >> 5) * 4 + ((n >> 4) & 3)) * 64
                      + ((n >> 3) & 1) * 32 + (o & 31)) * 8 + (n & 7);
        Vt[off] = f2bf(av[vt][r] + bv[o]);
      }
    }
  }
  __threadfence();
  cg::this_grid().sync();

  // ================= phase 2: fused attention ==============================
  {
    const int l31 = lane & 31;
    const int h   = lane >> 5;
    const int wq  = w & 3;          // q-subtile
    const int g   = w >> 2;         // kv-group
    const int bufbase = g * 2;
    const int q0 = n0;              // block's q rows = its proj pixels
    const int qw = q0 + wq * 32;

    const u16* Qp = Qb + ((size_t)b * NPIX + qw + l31) * DQK + h * 8;
    const v8h qf0 = *(const v8h*)(Qp);
    const v8h qf1 = *(const v8h*)(Qp + 16);
    const u16* Kp = Kb + ((size_t)b * NPIX + l31) * DQK + h * 8 + (size_t)g * 32 * 2048;
    const u16* Vg = Vt + ((size_t)b << 20) + (size_t)lane * 8 + (size_t)g * 32 * 16384;

    v16f acc[8];
#pragma unroll
    for (int i = 0; i < 8; ++i) acc[i] = (v16f){};
    float lsum = 0.f;
    const v16f vz = (v16f){};

    // prologue: stage(0); K(0) temp; S(0)+PACK -> pA; kc <- K(1)
    v8h kc0, kc1, kc2, kc3;
    v8s pA0, pA1, pA2, pA3, pB0, pB1, pB2, pB3;
    STAGE(0, bufbase);
    {
      v8h t0 = *(const v8h*)(Kp);
      v8h t1 = *(const v8h*)(Kp + 16);
      v8h t2 = *(const v8h*)(Kp + 1024);
      v8h t3 = *(const v8h*)(Kp + 1040);
      v16f sA = __builtin_amdgcn_mfma_f32_32x32x16_f16(t0, qf0, vz, 0, 0, 0);
      sA = __builtin_amdgcn_mfma_f32_32x32x16_f16(t1, qf1, sA, 0, 0, 0);
      PACK_TILE(sA, pA0, pA1);
      v16f sB = __builtin_amdgcn_mfma_f32_32x32x16_f16(t2, qf0, vz, 0, 0, 0);
      sB = __builtin_amdgcn_mfma_f32_32x32x16_f16(t3, qf1, sB, 0, 0, 0);
      PACK_TILE(sB, pA2, pA3);
      const u16* kp1 = Kp + 2048;
      kc0 = *(const v8h*)(kp1);
      kc1 = *(const v8h*)(kp1 + 16);
      kc2 = *(const v8h*)(kp1 + 1024);
      kc3 = *(const v8h*)(kp1 + 1040);
    }

#pragma unroll 1
    for (int t = 0; t < 16; ++t) {
      ASTEP(2 * t,     0, pA0, pA1, pA2, pA3, pB0, pB1, pB2, pB3);
      ASTEP(2 * t + 1, 1, pB0, pB1, pB2, pB3, pA0, pA1, pA2, pA3);
    }

    // epilogue: combine kv-groups (pure addition), scale, store
    lsum += __shfl_xor(lsum, 32);

    __syncthreads();
    float* Cb = (float*)&SB[0][0][0][0];
    if (w >= 4) {
      const int w4 = w - 4;
#pragma unroll
      for (int ct = 0; ct < 8; ++ct)
#pragma unroll
        for (int k = 0; k < 4; ++k) {
          v4f c = {acc[ct][k * 4 + 0], acc[ct][k * 4 + 1],
                   acc[ct][k * 4 + 2], acc[ct][k * 4 + 3]};
          *(v4f*)(Cb + (((w4 * 32 + ct * 4 + k) * 64 + lane) << 2)) = c;
        }
      if (lane < 32) Ls2[w4][l31] = lsum;
    }
    __syncthreads();
    if (w < 4) {
      const float linv = 1.0f / (lsum + Ls2[w][l31]);
#pragma unroll
      for (int ct = 0; ct < 8; ++ct)
#pragma unroll
        for (int k = 0; k < 4; ++k) {
          v4f c = *(const v4f*)(Cb + (((w * 32 + ct * 4 + k) * 64 + lane) << 2));
          acc[ct][k * 4 + 0] += c[0]; acc[ct][k * 4 + 1] += c[1];
          acc[ct][k * 4 + 2] += c[2]; acc[ct][k * 4 + 3] += c[3];
        }
      float* op = out + (size_t)b * NC * NPIX + q0 + wq * 32 + l31;
#pragma unroll
      for (int ct = 0; ct < 8; ++ct)
#pragma unroll
        for (int r = 0; r < 16; ++r) {
          const int ch = ct * 32 + (r & 3) + ((r >> 2) << 3) + (h << 2);
          op[(size_t)ch * NPIX] = acc[ct][r] * linv;
        }
    }
  }
}

extern "C" void kernel_launch(void* const* d_in, const int* in_sizes, int n_in,
                              void* d_out, int out_size, void* d_ws, size_t ws_size,
                              hipStream_t stream) {
  const float* x  = (const float*)d_in[0];
  const float* y  = (const float*)d_in[1];
  const float* Wq = (const float*)d_in[2];
  const float* bq = (const float*)d_in[3];
  const float* Wk = (const float*)d_in[4];
  const float* bk = (const float*)d_in[5];
  const float* Wv = (const float*)d_in[6];
  const float* bv = (const float*)d_in[7];
  float* out = (float*)d_out;

  // ws: Qb 2MB | Kb 2MB | Vt 16MB | Whq/Whk/Whv 160KB  ~= 20.2MB
  u16* Qb  = (u16*)d_ws;
  u16* Kb  = Qb + (size_t)NB * NPIX * DQK;
  u16* Vt  = Kb + (size_t)NB * NPIX * DQK;
  u16* Whq = Vt + (size_t)NB * NC * NPIX;
  u16* Whk = Whq + 32 * 256;
  u16* Whv = Whk + 32 * 256;

  void* args[] = {&x, &y, &Wq, &bq, &Wk, &bk, &Wv, &bv,
                  &Qb, &Kb, &Vt, &Whq, &Whk, &Whv, &out};
  hipLaunchCooperativeKernel((void*)fused_all, dim3(256), dim3(512), args, 0, stream);
}

// Round 7
// 239.250 us; speedup vs baseline: 1.7128x; 1.7128x over previous
//
#include <hip/hip_runtime.h>

typedef unsigned short u16;
typedef _Float16 f16;
typedef __attribute__((ext_vector_type(8))) short v8s;
typedef __attribute__((ext_vector_type(4))) short v4s;
typedef __attribute__((ext_vector_type(8))) f16   v8h;
typedef __attribute__((ext_vector_type(4))) float v4f;
typedef __attribute__((ext_vector_type(16))) float v16f;
typedef __attribute__((ext_vector_type(4))) unsigned v4u;

#define NB   8
#define NC   256
#define DQK  32
#define NPIX 4096

__device__ __forceinline__ u16 f2bf(float f) {
  unsigned u = __builtin_bit_cast(unsigned, f);
  u += 0x7FFFu + ((u >> 16) & 1u);   // RNE
  return (u16)(u >> 16);
}
__device__ __forceinline__ u16 f2h(float f) {
  return __builtin_bit_cast(u16, (f16)f);   // v_cvt_f16_f32, RNE
}
__device__ __forceinline__ unsigned cvt_pk_bf16(float lo, float hi) {
  unsigned r;
  asm("v_cvt_pk_bf16_f32 %0, %1, %2" : "=v"(r) : "v"(lo), "v"(hi));
  return r;
}
// raw v_exp_f32: exponents here are in ~[-91,-18] -> normal range, no ocml fixup needed
__device__ __forceinline__ float fast_exp2(float x) {
  float r;
  asm("v_exp_f32 %0, %1" : "=v"(r) : "v"(x));
  return r;
}

// ---- W -> fp16 (layouts already [o][c] row-major, elementwise convert) ----
__global__ __launch_bounds__(256)
void convert_w(const float* __restrict__ Wq, const float* __restrict__ Wk,
               const float* __restrict__ Wv,
               u16* __restrict__ Whq, u16* __restrict__ Whk, u16* __restrict__ Whv) {
  int i = blockIdx.x * 256 + threadIdx.x;   // 0..81919
  if (i < 8192)       Whq[i]         = f2h(Wq[i]);
  else if (i < 16384) Whk[i - 8192]  = f2h(Wk[i - 8192]);
  else                Whv[i - 16384] = f2h(Wv[i - 16384]);
}

// ---- Direct-gather projections: NO LDS, NO barriers ----
// B-frag built straight from global: lane needs x[c..c+8][n] (8 dword loads
// at stride 4096, 16-lane coalesced = 64B/quad, lines fully used across the
// block's 4 waves).  Kills the LDS transpose (64 scalar ds ops + 2 barriers
// per cs) that made the staged version LDS-pipe/barrier-bound.  Accumulation
// order identical to the staged version -> bit-identical output.
// V output in FRAG-LINEAR layout for the attn kernel's LDS staging:
// u16 index = (((b*64 + (kv>>6))*32 + (ch>>5)*4 + ((kv>>4)&3))*64
//              + ((kv>>3)&1)*32 + (ch&31))*8 + (kv&7)
__global__ __launch_bounds__(256, 2)
void proj_direct(const float* __restrict__ x, const float* __restrict__ y,
                 const u16* __restrict__ Whq, const float* __restrict__ bq,
                 const u16* __restrict__ Whk, const float* __restrict__ bk,
                 const u16* __restrict__ Whv, const float* __restrict__ bv,
                 u16* __restrict__ Qb, u16* __restrict__ Kb, u16* __restrict__ Vt) {
  const int tid = threadIdx.x, w = tid >> 6, lane = tid & 63;
  const int lr = lane & 15, quad = lane >> 4;
  const int b = blockIdx.x & 7;                    // XCD-affine batch
  const int n0 = (blockIdx.x >> 3) * 64;
  const int n = n0 + w * 16 + lr;
  const size_t bn = ((size_t)b << 12) + n;

  const float* __restrict__ xp = x + ((size_t)b << 20) + n;
  const float* __restrict__ yp = y + ((size_t)b << 20) + n;

  v4f aq[2], ak[2], av[16];
#pragma unroll
  for (int ot = 0; ot < 2; ++ot) { aq[ot] = (v4f){0.f,0.f,0.f,0.f}; ak[ot] = (v4f){0.f,0.f,0.f,0.f}; }
#pragma unroll
  for (int vt = 0; vt < 16; ++vt) av[vt] = (v4f){0.f,0.f,0.f,0.f};

#pragma unroll
  for (int cs = 0; cs < 4; ++cs) {
    // gather B-frags for this c-subtile (lane: c = cs*64 + {0,32} + quad*8 + j)
    v8h xb0, xb1, yb0, yb1;
#pragma unroll
    for (int j = 0; j < 8; ++j) {
      const size_t c0 = (size_t)(cs * 64 + quad * 8 + j) * NPIX;
      const size_t c1 = (size_t)(cs * 64 + 32 + quad * 8 + j) * NPIX;
      xb0[j] = (f16)xp[c0];
      xb1[j] = (f16)xp[c1];
      yb0[j] = (f16)yp[c0];
      yb1[j] = (f16)yp[c1];
    }

    // Q and K partials (2 o-tiles each)
#pragma unroll
    for (int ot = 0; ot < 2; ++ot) {
      const u16* wqp = Whq + (ot * 16 + lr) * 256 + cs * 64 + quad * 8;
      const u16* wkp = Whk + (ot * 16 + lr) * 256 + cs * 64 + quad * 8;
      aq[ot] = __builtin_amdgcn_mfma_f32_16x16x32_f16(*(const v8h*)(wqp),      xb0, aq[ot], 0, 0, 0);
      aq[ot] = __builtin_amdgcn_mfma_f32_16x16x32_f16(*(const v8h*)(wqp + 32), xb1, aq[ot], 0, 0, 0);
      ak[ot] = __builtin_amdgcn_mfma_f32_16x16x32_f16(*(const v8h*)(wkp),      yb0, ak[ot], 0, 0, 0);
      ak[ot] = __builtin_amdgcn_mfma_f32_16x16x32_f16(*(const v8h*)(wkp + 32), yb1, ak[ot], 0, 0, 0);
    }
    // V partials (16 o-tiles)
#pragma unroll
    for (int vt = 0; vt < 16; ++vt) {
      const u16* wvp = Whv + (vt * 16 + lr) * 256 + cs * 64 + quad * 8;
      av[vt] = __builtin_amdgcn_mfma_f32_16x16x32_f16(*(const v8h*)(wvp),      yb0, av[vt], 0, 0, 0);
      av[vt] = __builtin_amdgcn_mfma_f32_16x16x32_f16(*(const v8h*)(wvp + 32), yb1, av[vt], 0, 0, 0);
    }
  }

  // epilogue: Q/K bias + fp16 store (pixel-major [n][32])
#pragma unroll
  for (int ot = 0; ot < 2; ++ot) {
    v4f bqv = *(const v4f*)(bq + ot * 16 + quad * 4);
    v4f bkv = *(const v4f*)(bk + ot * 16 + quad * 4);
    v4s q4, k4;
#pragma unroll
    for (int r = 0; r < 4; ++r) {
      q4[r] = (short)f2h(aq[ot][r] + bqv[r]);
      k4[r] = (short)f2h(ak[ot][r] + bkv[r]);
    }
    *(v4s*)(Qb + bn * DQK + ot * 16 + quad * 4) = q4;
    *(v4s*)(Kb + bn * DQK + ot * 16 + quad * 4) = k4;
  }

  // epilogue: V bias + frag-linear bf16 store
#pragma unroll
  for (int vt = 0; vt < 16; ++vt) {
#pragma unroll
    for (int r = 0; r < 4; ++r) {
      int o = vt * 16 + quad * 4 + r;
      size_t off = ((((size_t)b * 64 + (n >> 6)) * 32 + (o >> 5) * 4 + ((n >> 4) & 3)) * 64
                    + ((n >> 3) & 1) * 32 + (o & 31)) * 8 + (n & 7);
      Vt[off] = f2bf(av[vt][r] + bv[o]);
    }
  }
}

// ---- Fused attention: in-block kv-split x2 for 2 waves/SIMD ----
// (round-5 version, unchanged: 99.5 us measured, MfmaUtil 33, conflicts 0)
#define L2E  1.44269504f
#define SHFT -48.0f

// From S tile (32 kv) produce PV B-frags for its two 16-kv blocks.
// reg r of S: kv = (r&3) + 8*(r>>2) + 4*(lane>>5).
#define PACK_TILE(S, PBLO, PBHI)                                              \
  {                                                                           \
    float e0  = fast_exp2(fmaf(S[0],  L2E, SHFT));                            \
    float e1  = fast_exp2(fmaf(S[1],  L2E, SHFT));                            \
    float e2  = fast_exp2(fmaf(S[2],  L2E, SHFT));                            \
    float e3  = fast_exp2(fmaf(S[3],  L2E, SHFT));                            \
    float e4  = fast_exp2(fmaf(S[4],  L2E, SHFT));                            \
    float e5  = fast_exp2(fmaf(S[5],  L2E, SHFT));                            \
    float e6  = fast_exp2(fmaf(S[6],  L2E, SHFT));                            \
    float e7  = fast_exp2(fmaf(S[7],  L2E, SHFT));                            \
    float e8  = fast_exp2(fmaf(S[8],  L2E, SHFT));                            \
    float e9  = fast_exp2(fmaf(S[9],  L2E, SHFT));                            \
    float e10 = fast_exp2(fmaf(S[10], L2E, SHFT));                            \
    float e11 = fast_exp2(fmaf(S[11], L2E, SHFT));                            \
    float e12 = fast_exp2(fmaf(S[12], L2E, SHFT));                            \
    float e13 = fast_exp2(fmaf(S[13], L2E, SHFT));                            \
    float e14 = fast_exp2(fmaf(S[14], L2E, SHFT));                            \
    float e15 = fast_exp2(fmaf(S[15], L2E, SHFT));                            \
    lsum += (((e0 + e1) + (e2 + e3)) + ((e4 + e5) + (e6 + e7)))               \
          + (((e8 + e9) + (e10 + e11)) + ((e12 + e13) + (e14 + e15)));        \
    unsigned u00 = cvt_pk_bf16(e0,  e1),  u01 = cvt_pk_bf16(e2,  e3);         \
    unsigned u10 = cvt_pk_bf16(e4,  e5),  u11 = cvt_pk_bf16(e6,  e7);         \
    unsigned u20 = cvt_pk_bf16(e8,  e9),  u21 = cvt_pk_bf16(e10, e11);        \
    unsigned u30 = cvt_pk_bf16(e12, e13), u31 = cvt_pk_bf16(e14, e15);        \
    asm("v_permlane32_swap_b32 %0, %1" : "+v"(u00), "+v"(u10));               \
    asm("v_permlane32_swap_b32 %0, %1" : "+v"(u01), "+v"(u11));               \
    asm("v_permlane32_swap_b32 %0, %1" : "+v"(u20), "+v"(u30));               \
    asm("v_permlane32_swap_b32 %0, %1" : "+v"(u21), "+v"(u31));               \
    PBLO = __builtin_bit_cast(v8s, (v4u){u00, u01, u10, u11});                \
    PBHI = __builtin_bit_cast(v8s, (v4u){u20, u21, u30, u31});                \
  }

__global__ __launch_bounds__(512, 2)
void attn_kernel(const u16* __restrict__ Qb, const u16* __restrict__ Kb,
                 const u16* __restrict__ Vt, float* __restrict__ out) {
  __shared__ __attribute__((aligned(16))) u16 Vb[4][32][64][8];   // 128 KiB
  __shared__ float Ls2[4][32];

  const int tid  = threadIdx.x;
  const int w    = tid >> 6;      // 0..7
  const int lane = tid & 63;
  const int l31  = lane & 31;
  const int wq   = w & 3;         // q-subtile
  const int g    = w >> 2;        // kv-group (0: steps 0..31, 1: steps 32..63)
  const int bufbase = g * 2;

  const int b  = blockIdx.x & 7;            // XCD-affine batch mapping
  const int q0 = (blockIdx.x >> 3) << 7;    // 128 q per block
  const int qw = q0 + wq * 32;              // wave's 32 q

  // Q B-frags (two d-halves): lane holds col q = qw+l31, k = h*8+j
  const int h = lane >> 5;
  const u16* Qp = Qb + ((size_t)b * NPIX + qw + l31) * DQK + h * 8;
  const v8h qf0 = *(const v8h*)(Qp);
  const v8h qf1 = *(const v8h*)(Qp + 16);

  // K A-frag base for this group's kv range
  const u16* Kp = Kb + ((size_t)b * NPIX + l31) * DQK + h * 8 + (size_t)g * 32 * 2048;

  // V frag-linear global for this group's kv range
  const u16* Vg = Vt + ((size_t)b << 20) + (size_t)lane * 8 + (size_t)g * 32 * 16384;

  v16f acc[8];
#pragma unroll
  for (int i = 0; i < 8; ++i) acc[i] = (v16f){};
  float lsum = 0.f;
  const v16f vz = (v16f){};

  // ---- prologue: stage(0); K(0); S(0)+pack -> pB; K(1) ----
#pragma unroll
  for (int j = 0; j < 8; ++j) {
    const int f = wq * 8 + j;
    __builtin_amdgcn_global_load_lds(
        (const __attribute__((address_space(1))) unsigned*)(Vg + (size_t)f * 512),
        (__attribute__((address_space(3))) unsigned*)(&Vb[bufbase][f][0][0]), 16, 0, 0);
  }
  v8h kc0 = *(const v8h*)(Kp);
  v8h kc1 = *(const v8h*)(Kp + 16);
  v8h kc2 = *(const v8h*)(Kp + 1024);
  v8h kc3 = *(const v8h*)(Kp + 1040);
  v8h kn0 = kc0, kn1 = kc1, kn2 = kc2, kn3 = kc3;

  v8s pB0, pB1, pB2, pB3;
  {
    v16f sA = __builtin_amdgcn_mfma_f32_32x32x16_f16(kc0, qf0, vz, 0, 0, 0);
    sA = __builtin_amdgcn_mfma_f32_32x32x16_f16(kc1, qf1, sA, 0, 0, 0);
    v16f sB = __builtin_amdgcn_mfma_f32_32x32x16_f16(kc2, qf0, vz, 0, 0, 0);
    sB = __builtin_amdgcn_mfma_f32_32x32x16_f16(kc3, qf1, sB, 0, 0, 0);
    PACK_TILE(sA, pB0, pB1);
    PACK_TILE(sB, pB2, pB3);
  }
  {
    const u16* kp1 = Kp + 2048;
    kc0 = *(const v8h*)(kp1);
    kc1 = *(const v8h*)(kp1 + 16);
    kc2 = *(const v8h*)(kp1 + 1024);
    kc3 = *(const v8h*)(kp1 + 1040);
  }

  // ---- main loop (32 steps per group) ----
#pragma unroll 1
  for (int it = 0; it < 32; ++it) {
    const int pp = it & 1;
    __builtin_amdgcn_sched_barrier(0);
    if (it < 31) {
      asm volatile("s_waitcnt vmcnt(4)" ::: "memory");   // stage(it) landed
    } else {
      asm volatile("s_waitcnt vmcnt(0)" ::: "memory");
    }
    __builtin_amdgcn_s_barrier();                        // all waves' stage(it) landed
    __builtin_amdgcn_sched_barrier(0);

    if (it < 31) {   // stage(it+1) into other parity buffer
#pragma unroll
      for (int j = 0; j < 8; ++j) {
        const int f = wq * 8 + j;
        __builtin_amdgcn_global_load_lds(
            (const __attribute__((address_space(1))) unsigned*)(Vg + ((size_t)(it + 1) * 32 + f) * 512),
            (__attribute__((address_space(3))) unsigned*)(&Vb[bufbase + (pp ^ 1)][f][0][0]), 16, 0, 0);
      }
    }

    // PV(it): 32 conflict-free ds_read_b128 + 32 MFMA (8 independent chains)
    __builtin_amdgcn_s_setprio(1);
#pragma unroll
    for (int ct = 0; ct < 8; ++ct) {
      v8s vf0 = *(const v8s*)(&Vb[bufbase + pp][ct * 4 + 0][lane][0]);
      v8s vf1 = *(const v8s*)(&Vb[bufbase + pp][ct * 4 + 1][lane][0]);
      v8s vf2 = *(const v8s*)(&Vb[bufbase + pp][ct * 4 + 2][lane][0]);
      v8s vf3 = *(const v8s*)(&Vb[bufbase + pp][ct * 4 + 3][lane][0]);
      acc[ct] = __builtin_amdgcn_mfma_f32_32x32x16_bf16(vf0, pB0, acc[ct], 0, 0, 0);
      acc[ct] = __builtin_amdgcn_mfma_f32_32x32x16_bf16(vf1, pB1, acc[ct], 0, 0, 0);
      acc[ct] = __builtin_amdgcn_mfma_f32_32x32x16_bf16(vf2, pB2, acc[ct], 0, 0, 0);
      acc[ct] = __builtin_amdgcn_mfma_f32_32x32x16_bf16(vf3, pB3, acc[ct], 0, 0, 0);
    }
    __builtin_amdgcn_s_setprio(0);

    if (it < 31) {
      // S(it+1) on K(it+1) regs (stage(it+1) stays in flight across this wait)
      v16f sA = __builtin_amdgcn_mfma_f32_32x32x16_f16(kc0, qf0, vz, 0, 0, 0);
      sA = __builtin_amdgcn_mfma_f32_32x32x16_f16(kc1, qf1, sA, 0, 0, 0);
      v16f sB = __builtin_amdgcn_mfma_f32_32x32x16_f16(kc2, qf0, vz, 0, 0, 0);
      sB = __builtin_amdgcn_mfma_f32_32x32x16_f16(kc3, qf1, sB, 0, 0, 0);
      if (it < 30) {   // K(it+2)
        const u16* kp2 = Kp + (size_t)(it + 2) * 2048;
        kn0 = *(const v8h*)(kp2);
        kn1 = *(const v8h*)(kp2 + 16);
        kn2 = *(const v8h*)(kp2 + 1024);
        kn3 = *(const v8h*)(kp2 + 1040);
      }
      PACK_TILE(sA, pB0, pB1);
      PACK_TILE(sB, pB2, pB3);
      kc0 = kn0; kc1 = kn1; kc2 = kn2; kc3 = kn3;
    }
  }

  // ---- epilogue: combine kv-groups (pure addition), scale, store ----
  lsum += __shfl_xor(lsum, 32);      // fold h halves; lane's q = l31

  __syncthreads();                   // all PV reads of Vb complete -> scratch reuse safe
  float* Cb = (float*)&Vb[0][0][0][0];
  if (w >= 4) {
    const int w4 = w - 4;
#pragma unroll
    for (int ct = 0; ct < 8; ++ct)
#pragma unroll
      for (int k = 0; k < 4; ++k) {
        v4f c = {acc[ct][k * 4 + 0], acc[ct][k * 4 + 1],
                 acc[ct][k * 4 + 2], acc[ct][k * 4 + 3]};
        *(v4f*)(Cb + (((w4 * 32 + ct * 4 + k) * 64 + lane) << 2)) = c;   // 16B/lane contig
      }
    if (lane < 32) Ls2[w4][l31] = lsum;
  }
  __syncthreads();
  if (w < 4) {
    const float linv = 1.0f / (lsum + Ls2[w][l31]);
#pragma unroll
    for (int ct = 0; ct < 8; ++ct)
#pragma unroll
      for (int k = 0; k < 4; ++k) {
        v4f c = *(const v4f*)(Cb + (((w * 32 + ct * 4 + k) * 64 + lane) << 2));
        acc[ct][k * 4 + 0] += c[0]; acc[ct][k * 4 + 1] += c[1];
        acc[ct][k * 4 + 2] += c[2]; acc[ct][k * 4 + 3] += c[3];
      }

    float* op = out + (size_t)b * NC * NPIX + q0 + wq * 32 + l31;
#pragma unroll
    for (int ct = 0; ct < 8; ++ct)
#pragma unroll
      for (int r = 0; r < 16; ++r) {
        const int ch = ct * 32 + (r & 3) + ((r >> 2) << 3) + (h << 2);
        op[(size_t)ch * NPIX] = acc[ct][r] * linv;
      }
  }
}

extern "C" void kernel_launch(void* const* d_in, const int* in_sizes, int n_in,
                              void* d_out, int out_size, void* d_ws, size_t ws_size,
                              hipStream_t stream) {
  const float* x  = (const float*)d_in[0];
  const float* y  = (const float*)d_in[1];
  const float* Wq = (const float*)d_in[2];
  const float* bq = (const float*)d_in[3];
  const float* Wk = (const float*)d_in[4];
  const float* bk = (const float*)d_in[5];
  const float* Wv = (const float*)d_in[6];
  const float* bv = (const float*)d_in[7];
  float* out = (float*)d_out;

  // ws: Qb 2MB | Kb 2MB | Vt 16MB | Whq/Whk/Whv 160KB  ~= 20.2MB
  u16* Qb  = (u16*)d_ws;
  u16* Kb  = Qb + (size_t)NB * NPIX * DQK;
  u16* Vt  = Kb + (size_t)NB * NPIX * DQK;
  u16* Whq = Vt + (size_t)NB * NC * NPIX;
  u16* Whk = Whq + 32 * 256;
  u16* Whv = Whk + 32 * 256;

  hipLaunchKernelGGL(convert_w, dim3(320), dim3(256), 0, stream, Wq, Wk, Wv, Whq, Whk, Whv);
  hipLaunchKernelGGL(proj_direct, dim3(512), dim3(256), 0, stream,
                     x, y, Whq, bq, Whk, bk, Whv, bv, Qb, Kb, Vt);
  hipLaunchKernelGGL(attn_kernel, dim3(256), dim3(512), 0, stream, Qb, Kb, Vt, out);
}